// Round 12
// baseline (870.958 us; speedup 1.0000x reference)
//
#include <hip/hip_runtime.h>

// EdgeGCN v5: coarse bucket sort (128 dst/bucket) + LDS-atomic aggregation.
// v4->v5: kill fine sort, per-node CSR, gather, h1s2, uv. Aggregation reads
// packed edges per bucket and ds_add_f32's into an LDS tile; layer epilogues
// (relu+W2 / Wfc dot) fused into the flush. GPART back to 256 (write
// granularity beat occupancy in v4); hist/part get int4 x4-edge ILP.

constexpr int NN = 100000;
constexpr int NE = 3200000;
constexpr int FI = 128;
constexpr int HD = 16;
constexpr int SHIFT = 7;                    // 128 nodes per bucket
constexpr int KB = (NN + 127) >> 7;         // 782 buckets
constexpr int GPART = 256;                  // partition/hist blocks
constexpr int CH = NE / GPART;              // 12500 edges per block (exact)
constexpr int M = KB * GPART;               // 200192 histogram entries
constexpr int NBLK1 = M / 512;              // 391 scan blocks (exact)

// Per-block LDS histogram of buckets, written transposed HT[k*G+b]. int4 x4 ILP.
__global__ __launch_bounds__(256) void k_hist(const int* __restrict__ dst,
                                              unsigned* __restrict__ HT) {
    __shared__ unsigned cnt[KB];
    for (int i = threadIdx.x; i < KB; i += 256) cnt[i] = 0;
    __syncthreads();
    const int4* dv = reinterpret_cast<const int4*>(dst) + blockIdx.x * (CH / 4);
    for (int v = threadIdx.x; v < CH / 4; v += 256) {
        int4 d4 = dv[v];
        atomicAdd(&cnt[d4.x >> SHIFT], 1u);
        atomicAdd(&cnt[d4.y >> SHIFT], 1u);
        atomicAdd(&cnt[d4.z >> SHIFT], 1u);
        atomicAdd(&cnt[d4.w >> SHIFT], 1u);
    }
    __syncthreads();
    for (int k = threadIdx.x; k < KB; k += 256)
        HT[(size_t)k * GPART + blockIdx.x] = cnt[k];
}

// Scan stage A: 512 elems/block -> pre, block totals -> bs.
__global__ __launch_bounds__(256) void k_scanA(const unsigned* __restrict__ in,
                                               unsigned* __restrict__ pre,
                                               unsigned* __restrict__ bs, int n) {
    __shared__ unsigned tsum[256];
    int t = threadIdx.x;
    int base = blockIdx.x * 512;
    int i0 = base + 2 * t, i1 = i0 + 1;
    unsigned a = (i0 < n) ? in[i0] : 0u;
    unsigned b = (i1 < n) ? in[i1] : 0u;
    tsum[t] = a + b;
    __syncthreads();
    #pragma unroll
    for (int off = 1; off < 256; off <<= 1) {
        unsigned v = (t >= off) ? tsum[t - off] : 0u;
        __syncthreads();
        tsum[t] += v;
        __syncthreads();
    }
    unsigned excl = tsum[t] - (a + b);
    if (t == 255) bs[blockIdx.x] = tsum[255];
    if (i0 < n) pre[i0] = excl;
    if (i1 < n) pre[i1] = excl + a;
}

// Stage B: exclusive scan of bs[nb] (nb <= 512) in place.
__global__ __launch_bounds__(512) void k_scanB(unsigned* __restrict__ bs, int nb) {
    __shared__ unsigned tsum[512];
    int t = threadIdx.x;
    unsigned v = (t < nb) ? bs[t] : 0u;
    tsum[t] = v;
    __syncthreads();
    #pragma unroll
    for (int off = 1; off < 512; off <<= 1) {
        unsigned w = (t >= off) ? tsum[t - off] : 0u;
        __syncthreads();
        tsum[t] += w;
        __syncthreads();
    }
    if (t < nb) bs[t] = tsum[t] - v;
}

// Stage C: out[i] = pre[i] + bs[i/512]  (out = HT in place: global run starts).
__global__ __launch_bounds__(256) void k_scanC(const unsigned* __restrict__ pre,
                                               const unsigned* __restrict__ bs,
                                               unsigned* __restrict__ out, int n) {
    int i = blockIdx.x * 256 + threadIdx.x;
    if (i < n) out[i] = pre[i] + bs[i >> 9];
}

// Partition: block b scatters its CH edges into bucket-grouped EP (LDS cursors).
// EP entry packs (d & 127) << 17 | s   (s < 2^17). int4 x4 ILP.
__global__ __launch_bounds__(256) void k_part(const int* __restrict__ src,
                                              const int* __restrict__ dst,
                                              const unsigned* __restrict__ HT,
                                              unsigned* __restrict__ EP) {
    __shared__ unsigned cur[KB];
    int b = blockIdx.x;
    for (int k = threadIdx.x; k < KB; k += 256)
        cur[k] = HT[(size_t)k * GPART + b];
    __syncthreads();
    const int4* dv = reinterpret_cast<const int4*>(dst) + b * (CH / 4);
    const int4* sv = reinterpret_cast<const int4*>(src) + b * (CH / 4);
    for (int v = threadIdx.x; v < CH / 4; v += 256) {
        int4 d4 = dv[v];
        int4 s4 = sv[v];
        unsigned p0 = atomicAdd(&cur[d4.x >> SHIFT], 1u);
        unsigned p1 = atomicAdd(&cur[d4.y >> SHIFT], 1u);
        unsigned p2 = atomicAdd(&cur[d4.z >> SHIFT], 1u);
        unsigned p3 = atomicAdd(&cur[d4.w >> SHIFT], 1u);
        EP[p0] = ((unsigned)(d4.x & 127) << 17) | (unsigned)s4.x;
        EP[p1] = ((unsigned)(d4.y & 127) << 17) | (unsigned)s4.y;
        EP[p2] = ((unsigned)(d4.z & 127) << 17) | (unsigned)s4.z;
        EP[p3] = ((unsigned)(d4.w & 127) << 17) | (unsigned)s4.w;
    }
}

// Per-node degree -> dinv, from packed bucket edges (one block per bucket).
__global__ __launch_bounds__(256) void k_dinv(const unsigned* __restrict__ HT,
                                              const unsigned* __restrict__ EP,
                                              float* __restrict__ dinv) {
    __shared__ unsigned cnt[128];
    int k = blockIdx.x;
    if (threadIdx.x < 128) cnt[threadIdx.x] = 0;
    int s0 = (int)HT[(size_t)k * GPART];
    int s1 = (k == KB - 1) ? NE : (int)HT[(size_t)(k + 1) * GPART];
    __syncthreads();
    for (int j = s0 + (int)threadIdx.x; j < s1; j += 256)
        atomicAdd(&cnt[EP[j] >> 17], 1u);
    __syncthreads();
    if (threadIdx.x < 128) {
        int n = (k << SHIFT) + (int)threadIdx.x;
        if (n < NN) dinv[n] = rsqrtf((float)cnt[threadIdx.x] + 1.0f);
    }
}

// S = (x @ W1) * dinv
__global__ __launch_bounds__(256) void k_xw1(const float* __restrict__ x,
                                             const float* __restrict__ W1,
                                             const float* __restrict__ dinv,
                                             float* __restrict__ S) {
    int i = blockIdx.x * 256 + threadIdx.x;
    if (i >= NN) return;
    const float4* xr = reinterpret_cast<const float4*>(x + (size_t)i * FI);
    float acc[HD];
    #pragma unroll
    for (int k = 0; k < HD; ++k) acc[k] = 0.f;
    #pragma unroll 8
    for (int jc = 0; jc < FI / 4; ++jc) {
        float4 xv = xr[jc];
        const float* w = W1 + jc * 4 * HD;
        #pragma unroll
        for (int k = 0; k < HD; ++k)
            acc[k] += xv.x * w[k] + xv.y * w[HD + k] + xv.z * w[2 * HD + k] + xv.w * w[3 * HD + k];
    }
    float dv = dinv[i];
    float4* out = reinterpret_cast<float4*>(S + (size_t)i * HD);
    #pragma unroll
    for (int q = 0; q < 4; ++q)
        out[q] = make_float4(acc[q * 4 + 0] * dv, acc[q * 4 + 1] * dv,
                             acc[q * 4 + 2] * dv, acc[q * 4 + 3] * dv);
}

// Layer-1 aggregate + fused epilogue. One block per bucket; 16 lanes per edge
// ds_add into acc[128][17] (stride 17: atomic lanes conflict-free, flush reads
// stride-17 conflict-free). Flush: h1 = relu(dinv*(acc+S)+b1); S2 = (h1@W2)*dinv.
__global__ __launch_bounds__(256) void k_aggA(const unsigned* __restrict__ HT,
                                              const unsigned* __restrict__ EP,
                                              const float* __restrict__ S,
                                              const float* __restrict__ dinv,
                                              const float* __restrict__ b1,
                                              const float* __restrict__ W2,
                                              float* __restrict__ S2) {
    __shared__ float acc[128 * 17];
    __shared__ float w2[256];
    __shared__ float bb[16];
    int t = threadIdx.x;
    int k = blockIdx.x;
    w2[t] = W2[t];
    if (t < 16) bb[t] = b1[t];
    #pragma unroll
    for (int q = 0; q < 9; ++q) {
        int i = t + q * 256;
        if (i < 128 * 17) acc[i] = 0.f;
    }
    int s0 = (int)HT[(size_t)k * GPART];
    int s1 = (k == KB - 1) ? NE : (int)HT[(size_t)(k + 1) * GPART];
    __syncthreads();
    int lane = t & 15;
    int j = s0 + (t >> 4);
    for (; j + 48 < s1; j += 64) {
        unsigned p0 = EP[j], p1 = EP[j + 16], p2 = EP[j + 32], p3 = EP[j + 48];
        float v0 = S[(size_t)(p0 & 0x1FFFFu) * HD + lane];
        float v1 = S[(size_t)(p1 & 0x1FFFFu) * HD + lane];
        float v2 = S[(size_t)(p2 & 0x1FFFFu) * HD + lane];
        float v3 = S[(size_t)(p3 & 0x1FFFFu) * HD + lane];
        unsafeAtomicAdd(&acc[(p0 >> 17) * 17 + lane], v0);
        unsafeAtomicAdd(&acc[(p1 >> 17) * 17 + lane], v1);
        unsafeAtomicAdd(&acc[(p2 >> 17) * 17 + lane], v2);
        unsafeAtomicAdd(&acc[(p3 >> 17) * 17 + lane], v3);
    }
    for (; j < s1; j += 16) {
        unsigned p = EP[j];
        unsafeAtomicAdd(&acc[(p >> 17) * 17 + lane], S[(size_t)(p & 0x1FFFFu) * HD + lane]);
    }
    __syncthreads();
    if (t < 128) {
        int n = (k << SHIFT) + t;
        if (n < NN) {
            float dv = dinv[n];
            const float4* sr = reinterpret_cast<const float4*>(S + (size_t)n * HD);
            float h[HD];
            #pragma unroll
            for (int q = 0; q < 4; ++q) {
                float4 s = sr[q];
                h[q * 4 + 0] = fmaxf(dv * (acc[t * 17 + q * 4 + 0] + s.x) + bb[q * 4 + 0], 0.f);
                h[q * 4 + 1] = fmaxf(dv * (acc[t * 17 + q * 4 + 1] + s.y) + bb[q * 4 + 1], 0.f);
                h[q * 4 + 2] = fmaxf(dv * (acc[t * 17 + q * 4 + 2] + s.z) + bb[q * 4 + 2], 0.f);
                h[q * 4 + 3] = fmaxf(dv * (acc[t * 17 + q * 4 + 3] + s.w) + bb[q * 4 + 3], 0.f);
            }
            float4* o = reinterpret_cast<float4*>(S2 + (size_t)n * HD);
            #pragma unroll
            for (int q = 0; q < 4; ++q) {
                float r[4];
                #pragma unroll
                for (int c = 0; c < 4; ++c) {
                    float s = 0.f;
                    #pragma unroll
                    for (int jj = 0; jj < HD; ++jj) s += h[jj] * w2[jj * HD + q * 4 + c];
                    r[c] = s * dv;
                }
                o[q] = make_float4(r[0], r[1], r[2], r[3]);
            }
        }
    }
}

// Layer-2 aggregate + fused edge-scorer prep.
// Flush: h2 = dinv*(acc+S2)+b2; UV = (h2.Wfc[0:16], h2.Wfc[16:32]).
__global__ __launch_bounds__(256) void k_aggB(const unsigned* __restrict__ HT,
                                              const unsigned* __restrict__ EP,
                                              const float* __restrict__ S2,
                                              const float* __restrict__ dinv,
                                              const float* __restrict__ b2,
                                              const float* __restrict__ Wfc,
                                              float2* __restrict__ UV) {
    __shared__ float acc[128 * 17];
    __shared__ float wf[32];
    __shared__ float bb[16];
    int t = threadIdx.x;
    int k = blockIdx.x;
    if (t < 32) wf[t] = Wfc[t];
    if (t >= 32 && t < 48) bb[t - 32] = b2[t - 32];
    #pragma unroll
    for (int q = 0; q < 9; ++q) {
        int i = t + q * 256;
        if (i < 128 * 17) acc[i] = 0.f;
    }
    int s0 = (int)HT[(size_t)k * GPART];
    int s1 = (k == KB - 1) ? NE : (int)HT[(size_t)(k + 1) * GPART];
    __syncthreads();
    int lane = t & 15;
    int j = s0 + (t >> 4);
    for (; j + 48 < s1; j += 64) {
        unsigned p0 = EP[j], p1 = EP[j + 16], p2 = EP[j + 32], p3 = EP[j + 48];
        float v0 = S2[(size_t)(p0 & 0x1FFFFu) * HD + lane];
        float v1 = S2[(size_t)(p1 & 0x1FFFFu) * HD + lane];
        float v2 = S2[(size_t)(p2 & 0x1FFFFu) * HD + lane];
        float v3 = S2[(size_t)(p3 & 0x1FFFFu) * HD + lane];
        unsafeAtomicAdd(&acc[(p0 >> 17) * 17 + lane], v0);
        unsafeAtomicAdd(&acc[(p1 >> 17) * 17 + lane], v1);
        unsafeAtomicAdd(&acc[(p2 >> 17) * 17 + lane], v2);
        unsafeAtomicAdd(&acc[(p3 >> 17) * 17 + lane], v3);
    }
    for (; j < s1; j += 16) {
        unsigned p = EP[j];
        unsafeAtomicAdd(&acc[(p >> 17) * 17 + lane], S2[(size_t)(p & 0x1FFFFu) * HD + lane]);
    }
    __syncthreads();
    if (t < 128) {
        int n = (k << SHIFT) + t;
        if (n < NN) {
            float dv = dinv[n];
            const float4* sr = reinterpret_cast<const float4*>(S2 + (size_t)n * HD);
            float u = 0.f, v = 0.f;
            #pragma unroll
            for (int q = 0; q < 4; ++q) {
                float4 s = sr[q];
                float h0 = dv * (acc[t * 17 + q * 4 + 0] + s.x) + bb[q * 4 + 0];
                float h1 = dv * (acc[t * 17 + q * 4 + 1] + s.y) + bb[q * 4 + 1];
                float h2 = dv * (acc[t * 17 + q * 4 + 2] + s.z) + bb[q * 4 + 2];
                float h3 = dv * (acc[t * 17 + q * 4 + 3] + s.w) + bb[q * 4 + 3];
                u += h0 * wf[q * 4 + 0] + h1 * wf[q * 4 + 1] + h2 * wf[q * 4 + 2] + h3 * wf[q * 4 + 3];
                v += h0 * wf[HD + q * 4 + 0] + h1 * wf[HD + q * 4 + 1] + h2 * wf[HD + q * 4 + 2] + h3 * wf[HD + q * 4 + 3];
            }
            UV[n] = make_float2(u, v);
        }
    }
}

__global__ __launch_bounds__(256) void k_pred(const int* __restrict__ src,
                                              const int* __restrict__ dst,
                                              const float2* __restrict__ UV,
                                              const float* __restrict__ bfc,
                                              float* __restrict__ out) {
    int t = blockIdx.x * 256 + threadIdx.x;       // NE/4 threads
    int4 s4 = reinterpret_cast<const int4*>(src)[t];
    int4 d4 = reinterpret_cast<const int4*>(dst)[t];
    float bb = bfc[0];
    float4 o;
    o.x = UV[s4.x].x + UV[d4.x].y + bb;
    o.y = UV[s4.y].x + UV[d4.y].y + bb;
    o.z = UV[s4.z].x + UV[d4.z].y + bb;
    o.w = UV[s4.w].x + UV[d4.w].y + bb;
    reinterpret_cast<float4*>(out)[t] = o;
}

extern "C" void kernel_launch(void* const* d_in, const int* in_sizes, int n_in,
                              void* d_out, int out_size, void* d_ws, size_t ws_size,
                              hipStream_t stream) {
    const float* x   = (const float*)d_in[0];
    const int*   ei  = (const int*)d_in[1];
    const float* W1  = (const float*)d_in[2];
    const float* b1  = (const float*)d_in[3];
    const float* W2  = (const float*)d_in[4];
    const float* b2  = (const float*)d_in[5];
    const float* Wfc = (const float*)d_in[6];
    const float* bfc = (const float*)d_in[7];
    const int* src = ei;            // edge_index[0]
    const int* dst = ei + NE;       // edge_index[1]

    // ws layout (4B units):
    //   HT[M] | BS[512] | PRE[M] | EP[E] | dinv[N] | S[16N] | S2[16N] | UV[2N]
    unsigned* ws32 = (unsigned*)d_ws;
    unsigned* HT   = ws32;
    unsigned* BS   = HT + M;
    unsigned* PRE  = BS + 512;
    unsigned* EP   = PRE + M;
    float*    dinv = (float*)(EP + NE);
    float*    S    = dinv + NN;
    float*    S2   = S + 16 * (size_t)NN;
    float2*   UV   = (float2*)(S2 + 16 * (size_t)NN);
    float* out = (float*)d_out;

    k_hist <<<GPART, 256, 0, stream>>>(dst, HT);
    k_scanA<<<NBLK1, 256, 0, stream>>>(HT, PRE, BS, M);
    k_scanB<<<1, 512, 0, stream>>>(BS, NBLK1);
    k_scanC<<<(M + 255) / 256, 256, 0, stream>>>(PRE, BS, HT, M);
    k_part <<<GPART, 256, 0, stream>>>(src, dst, HT, EP);
    k_dinv <<<KB, 256, 0, stream>>>(HT, EP, dinv);
    k_xw1  <<<(NN + 255) / 256, 256, 0, stream>>>(x, W1, dinv, S);
    k_aggA <<<KB, 256, 0, stream>>>(HT, EP, S, dinv, b1, W2, S2);
    k_aggB <<<KB, 256, 0, stream>>>(HT, EP, S2, dinv, b2, Wfc, UV);
    k_pred <<<NE / 4 / 256, 256, 0, stream>>>(src, dst, UV, bfc, out);
}

// Round 14
// 866.441 us; speedup vs baseline: 1.0052x; 1.0052x over previous
//
#include <hip/hip_runtime.h>

// EdgeGCN v6: v5 with two agg fixes.
// (1) unsafeAtomicAdd on __shared__ went down the flat/global-atomic path
//     (~4cy/lane serial => 333us, matched measurement). Use atomicAdd on the
//     LDS tile -> ds_add_f32 (bank-parallel, fire-and-forget).
// (2) agg blocks 256->512 threads: grid is 782 blocks (~3/CU), so 4-wave
//     blocks capped latency hiding at 12 waves/CU; 8-wave blocks give 24.

constexpr int NN = 100000;
constexpr int NE = 3200000;
constexpr int FI = 128;
constexpr int HD = 16;
constexpr int SHIFT = 7;                    // 128 nodes per bucket
constexpr int KB = (NN + 127) >> 7;         // 782 buckets
constexpr int GPART = 256;                  // partition/hist blocks
constexpr int CH = NE / GPART;              // 12500 edges per block (exact)
constexpr int M = KB * GPART;               // 200192 histogram entries
constexpr int NBLK1 = M / 512;              // 391 scan blocks (exact)

// Per-block LDS histogram of buckets, written transposed HT[k*G+b]. int4 x4 ILP.
__global__ __launch_bounds__(256) void k_hist(const int* __restrict__ dst,
                                              unsigned* __restrict__ HT) {
    __shared__ unsigned cnt[KB];
    for (int i = threadIdx.x; i < KB; i += 256) cnt[i] = 0;
    __syncthreads();
    const int4* dv = reinterpret_cast<const int4*>(dst) + blockIdx.x * (CH / 4);
    for (int v = threadIdx.x; v < CH / 4; v += 256) {
        int4 d4 = dv[v];
        atomicAdd(&cnt[d4.x >> SHIFT], 1u);
        atomicAdd(&cnt[d4.y >> SHIFT], 1u);
        atomicAdd(&cnt[d4.z >> SHIFT], 1u);
        atomicAdd(&cnt[d4.w >> SHIFT], 1u);
    }
    __syncthreads();
    for (int k = threadIdx.x; k < KB; k += 256)
        HT[(size_t)k * GPART + blockIdx.x] = cnt[k];
}

// Scan stage A: 512 elems/block -> pre, block totals -> bs.
__global__ __launch_bounds__(256) void k_scanA(const unsigned* __restrict__ in,
                                               unsigned* __restrict__ pre,
                                               unsigned* __restrict__ bs, int n) {
    __shared__ unsigned tsum[256];
    int t = threadIdx.x;
    int base = blockIdx.x * 512;
    int i0 = base + 2 * t, i1 = i0 + 1;
    unsigned a = (i0 < n) ? in[i0] : 0u;
    unsigned b = (i1 < n) ? in[i1] : 0u;
    tsum[t] = a + b;
    __syncthreads();
    #pragma unroll
    for (int off = 1; off < 256; off <<= 1) {
        unsigned v = (t >= off) ? tsum[t - off] : 0u;
        __syncthreads();
        tsum[t] += v;
        __syncthreads();
    }
    unsigned excl = tsum[t] - (a + b);
    if (t == 255) bs[blockIdx.x] = tsum[255];
    if (i0 < n) pre[i0] = excl;
    if (i1 < n) pre[i1] = excl + a;
}

// Stage B: exclusive scan of bs[nb] (nb <= 512) in place.
__global__ __launch_bounds__(512) void k_scanB(unsigned* __restrict__ bs, int nb) {
    __shared__ unsigned tsum[512];
    int t = threadIdx.x;
    unsigned v = (t < nb) ? bs[t] : 0u;
    tsum[t] = v;
    __syncthreads();
    #pragma unroll
    for (int off = 1; off < 512; off <<= 1) {
        unsigned w = (t >= off) ? tsum[t - off] : 0u;
        __syncthreads();
        tsum[t] += w;
        __syncthreads();
    }
    if (t < nb) bs[t] = tsum[t] - v;
}

// Stage C: out[i] = pre[i] + bs[i/512]  (out = HT in place: global run starts).
__global__ __launch_bounds__(256) void k_scanC(const unsigned* __restrict__ pre,
                                               const unsigned* __restrict__ bs,
                                               unsigned* __restrict__ out, int n) {
    int i = blockIdx.x * 256 + threadIdx.x;
    if (i < n) out[i] = pre[i] + bs[i >> 9];
}

// Partition: block b scatters its CH edges into bucket-grouped EP (LDS cursors).
// EP entry packs (d & 127) << 17 | s   (s < 2^17). int4 x4 ILP.
__global__ __launch_bounds__(256) void k_part(const int* __restrict__ src,
                                              const int* __restrict__ dst,
                                              const unsigned* __restrict__ HT,
                                              unsigned* __restrict__ EP) {
    __shared__ unsigned cur[KB];
    int b = blockIdx.x;
    for (int k = threadIdx.x; k < KB; k += 256)
        cur[k] = HT[(size_t)k * GPART + b];
    __syncthreads();
    const int4* dv = reinterpret_cast<const int4*>(dst) + b * (CH / 4);
    const int4* sv = reinterpret_cast<const int4*>(src) + b * (CH / 4);
    for (int v = threadIdx.x; v < CH / 4; v += 256) {
        int4 d4 = dv[v];
        int4 s4 = sv[v];
        unsigned p0 = atomicAdd(&cur[d4.x >> SHIFT], 1u);
        unsigned p1 = atomicAdd(&cur[d4.y >> SHIFT], 1u);
        unsigned p2 = atomicAdd(&cur[d4.z >> SHIFT], 1u);
        unsigned p3 = atomicAdd(&cur[d4.w >> SHIFT], 1u);
        EP[p0] = ((unsigned)(d4.x & 127) << 17) | (unsigned)s4.x;
        EP[p1] = ((unsigned)(d4.y & 127) << 17) | (unsigned)s4.y;
        EP[p2] = ((unsigned)(d4.z & 127) << 17) | (unsigned)s4.z;
        EP[p3] = ((unsigned)(d4.w & 127) << 17) | (unsigned)s4.w;
    }
}

// Per-node degree -> dinv, from packed bucket edges (one block per bucket).
__global__ __launch_bounds__(256) void k_dinv(const unsigned* __restrict__ HT,
                                              const unsigned* __restrict__ EP,
                                              float* __restrict__ dinv) {
    __shared__ unsigned cnt[128];
    int k = blockIdx.x;
    if (threadIdx.x < 128) cnt[threadIdx.x] = 0;
    int s0 = (int)HT[(size_t)k * GPART];
    int s1 = (k == KB - 1) ? NE : (int)HT[(size_t)(k + 1) * GPART];
    __syncthreads();
    for (int j = s0 + (int)threadIdx.x; j < s1; j += 256)
        atomicAdd(&cnt[EP[j] >> 17], 1u);
    __syncthreads();
    if (threadIdx.x < 128) {
        int n = (k << SHIFT) + (int)threadIdx.x;
        if (n < NN) dinv[n] = rsqrtf((float)cnt[threadIdx.x] + 1.0f);
    }
}

// S = (x @ W1) * dinv
__global__ __launch_bounds__(256) void k_xw1(const float* __restrict__ x,
                                             const float* __restrict__ W1,
                                             const float* __restrict__ dinv,
                                             float* __restrict__ S) {
    int i = blockIdx.x * 256 + threadIdx.x;
    if (i >= NN) return;
    const float4* xr = reinterpret_cast<const float4*>(x + (size_t)i * FI);
    float acc[HD];
    #pragma unroll
    for (int k = 0; k < HD; ++k) acc[k] = 0.f;
    #pragma unroll 8
    for (int jc = 0; jc < FI / 4; ++jc) {
        float4 xv = xr[jc];
        const float* w = W1 + jc * 4 * HD;
        #pragma unroll
        for (int k = 0; k < HD; ++k)
            acc[k] += xv.x * w[k] + xv.y * w[HD + k] + xv.z * w[2 * HD + k] + xv.w * w[3 * HD + k];
    }
    float dv = dinv[i];
    float4* out = reinterpret_cast<float4*>(S + (size_t)i * HD);
    #pragma unroll
    for (int q = 0; q < 4; ++q)
        out[q] = make_float4(acc[q * 4 + 0] * dv, acc[q * 4 + 1] * dv,
                             acc[q * 4 + 2] * dv, acc[q * 4 + 3] * dv);
}

// Layer-1 aggregate + fused epilogue. One 512-thread block per bucket; 32
// groups of 16 lanes; ds_add_f32 into acc[128][17]. Flush: h1 = relu(...),
// S2 = (h1@W2)*dinv.
__global__ __launch_bounds__(512) void k_aggA(const unsigned* __restrict__ HT,
                                              const unsigned* __restrict__ EP,
                                              const float* __restrict__ S,
                                              const float* __restrict__ dinv,
                                              const float* __restrict__ b1,
                                              const float* __restrict__ W2,
                                              float* __restrict__ S2) {
    __shared__ float acc[128 * 17];
    __shared__ float w2[256];
    __shared__ float bb[16];
    int t = threadIdx.x;
    int k = blockIdx.x;
    if (t < 256) w2[t] = W2[t];
    if (t < 16) bb[t] = b1[t];
    for (int i = t; i < 128 * 17; i += 512) acc[i] = 0.f;
    int s0 = (int)HT[(size_t)k * GPART];
    int s1 = (k == KB - 1) ? NE : (int)HT[(size_t)(k + 1) * GPART];
    __syncthreads();
    int lane = t & 15;
    int j = s0 + (t >> 4);                        // 32 groups
    for (; j + 96 < s1; j += 128) {
        unsigned p0 = EP[j], p1 = EP[j + 32], p2 = EP[j + 64], p3 = EP[j + 96];
        float v0 = S[(size_t)(p0 & 0x1FFFFu) * HD + lane];
        float v1 = S[(size_t)(p1 & 0x1FFFFu) * HD + lane];
        float v2 = S[(size_t)(p2 & 0x1FFFFu) * HD + lane];
        float v3 = S[(size_t)(p3 & 0x1FFFFu) * HD + lane];
        atomicAdd(&acc[(p0 >> 17) * 17 + lane], v0);
        atomicAdd(&acc[(p1 >> 17) * 17 + lane], v1);
        atomicAdd(&acc[(p2 >> 17) * 17 + lane], v2);
        atomicAdd(&acc[(p3 >> 17) * 17 + lane], v3);
    }
    for (; j < s1; j += 32) {
        unsigned p = EP[j];
        atomicAdd(&acc[(p >> 17) * 17 + lane], S[(size_t)(p & 0x1FFFFu) * HD + lane]);
    }
    __syncthreads();
    if (t < 128) {
        int n = (k << SHIFT) + t;
        if (n < NN) {
            float dv = dinv[n];
            const float4* sr = reinterpret_cast<const float4*>(S + (size_t)n * HD);
            float h[HD];
            #pragma unroll
            for (int q = 0; q < 4; ++q) {
                float4 s = sr[q];
                h[q * 4 + 0] = fmaxf(dv * (acc[t * 17 + q * 4 + 0] + s.x) + bb[q * 4 + 0], 0.f);
                h[q * 4 + 1] = fmaxf(dv * (acc[t * 17 + q * 4 + 1] + s.y) + bb[q * 4 + 1], 0.f);
                h[q * 4 + 2] = fmaxf(dv * (acc[t * 17 + q * 4 + 2] + s.z) + bb[q * 4 + 2], 0.f);
                h[q * 4 + 3] = fmaxf(dv * (acc[t * 17 + q * 4 + 3] + s.w) + bb[q * 4 + 3], 0.f);
            }
            float4* o = reinterpret_cast<float4*>(S2 + (size_t)n * HD);
            #pragma unroll
            for (int q = 0; q < 4; ++q) {
                float r[4];
                #pragma unroll
                for (int c = 0; c < 4; ++c) {
                    float s = 0.f;
                    #pragma unroll
                    for (int jj = 0; jj < HD; ++jj) s += h[jj] * w2[jj * HD + q * 4 + c];
                    r[c] = s * dv;
                }
                o[q] = make_float4(r[0], r[1], r[2], r[3]);
            }
        }
    }
}

// Layer-2 aggregate + fused edge-scorer prep (512-thread blocks).
// Flush: h2 = dinv*(acc+S2)+b2; UV = (h2.Wfc[0:16], h2.Wfc[16:32]).
__global__ __launch_bounds__(512) void k_aggB(const unsigned* __restrict__ HT,
                                              const unsigned* __restrict__ EP,
                                              const float* __restrict__ S2,
                                              const float* __restrict__ dinv,
                                              const float* __restrict__ b2,
                                              const float* __restrict__ Wfc,
                                              float2* __restrict__ UV) {
    __shared__ float acc[128 * 17];
    __shared__ float wf[32];
    __shared__ float bb[16];
    int t = threadIdx.x;
    int k = blockIdx.x;
    if (t < 32) wf[t] = Wfc[t];
    if (t >= 32 && t < 48) bb[t - 32] = b2[t - 32];
    for (int i = t; i < 128 * 17; i += 512) acc[i] = 0.f;
    int s0 = (int)HT[(size_t)k * GPART];
    int s1 = (k == KB - 1) ? NE : (int)HT[(size_t)(k + 1) * GPART];
    __syncthreads();
    int lane = t & 15;
    int j = s0 + (t >> 4);                        // 32 groups
    for (; j + 96 < s1; j += 128) {
        unsigned p0 = EP[j], p1 = EP[j + 32], p2 = EP[j + 64], p3 = EP[j + 96];
        float v0 = S2[(size_t)(p0 & 0x1FFFFu) * HD + lane];
        float v1 = S2[(size_t)(p1 & 0x1FFFFu) * HD + lane];
        float v2 = S2[(size_t)(p2 & 0x1FFFFu) * HD + lane];
        float v3 = S2[(size_t)(p3 & 0x1FFFFu) * HD + lane];
        atomicAdd(&acc[(p0 >> 17) * 17 + lane], v0);
        atomicAdd(&acc[(p1 >> 17) * 17 + lane], v1);
        atomicAdd(&acc[(p2 >> 17) * 17 + lane], v2);
        atomicAdd(&acc[(p3 >> 17) * 17 + lane], v3);
    }
    for (; j < s1; j += 32) {
        unsigned p = EP[j];
        atomicAdd(&acc[(p >> 17) * 17 + lane], S2[(size_t)(p & 0x1FFFFu) * HD + lane]);
    }
    __syncthreads();
    if (t < 128) {
        int n = (k << SHIFT) + t;
        if (n < NN) {
            float dv = dinv[n];
            const float4* sr = reinterpret_cast<const float4*>(S2 + (size_t)n * HD);
            float u = 0.f, v = 0.f;
            #pragma unroll
            for (int q = 0; q < 4; ++q) {
                float4 s = sr[q];
                float h0 = dv * (acc[t * 17 + q * 4 + 0] + s.x) + bb[q * 4 + 0];
                float h1 = dv * (acc[t * 17 + q * 4 + 1] + s.y) + bb[q * 4 + 1];
                float h2 = dv * (acc[t * 17 + q * 4 + 2] + s.z) + bb[q * 4 + 2];
                float h3 = dv * (acc[t * 17 + q * 4 + 3] + s.w) + bb[q * 4 + 3];
                u += h0 * wf[q * 4 + 0] + h1 * wf[q * 4 + 1] + h2 * wf[q * 4 + 2] + h3 * wf[q * 4 + 3];
                v += h0 * wf[HD + q * 4 + 0] + h1 * wf[HD + q * 4 + 1] + h2 * wf[HD + q * 4 + 2] + h3 * wf[HD + q * 4 + 3];
            }
            UV[n] = make_float2(u, v);
        }
    }
}

__global__ __launch_bounds__(256) void k_pred(const int* __restrict__ src,
                                              const int* __restrict__ dst,
                                              const float2* __restrict__ UV,
                                              const float* __restrict__ bfc,
                                              float* __restrict__ out) {
    int t = blockIdx.x * 256 + threadIdx.x;       // NE/4 threads
    int4 s4 = reinterpret_cast<const int4*>(src)[t];
    int4 d4 = reinterpret_cast<const int4*>(dst)[t];
    float bb = bfc[0];
    float4 o;
    o.x = UV[s4.x].x + UV[d4.x].y + bb;
    o.y = UV[s4.y].x + UV[d4.y].y + bb;
    o.z = UV[s4.z].x + UV[d4.z].y + bb;
    o.w = UV[s4.w].x + UV[d4.w].y + bb;
    reinterpret_cast<float4*>(out)[t] = o;
}

extern "C" void kernel_launch(void* const* d_in, const int* in_sizes, int n_in,
                              void* d_out, int out_size, void* d_ws, size_t ws_size,
                              hipStream_t stream) {
    const float* x   = (const float*)d_in[0];
    const int*   ei  = (const int*)d_in[1];
    const float* W1  = (const float*)d_in[2];
    const float* b1  = (const float*)d_in[3];
    const float* W2  = (const float*)d_in[4];
    const float* b2  = (const float*)d_in[5];
    const float* Wfc = (const float*)d_in[6];
    const float* bfc = (const float*)d_in[7];
    const int* src = ei;            // edge_index[0]
    const int* dst = ei + NE;       // edge_index[1]

    // ws layout (4B units):
    //   HT[M] | BS[512] | PRE[M] | EP[E] | dinv[N] | S[16N] | S2[16N] | UV[2N]
    unsigned* ws32 = (unsigned*)d_ws;
    unsigned* HT   = ws32;
    unsigned* BS   = HT + M;
    unsigned* PRE  = BS + 512;
    unsigned* EP   = PRE + M;
    float*    dinv = (float*)(EP + NE);
    float*    S    = dinv + NN;
    float*    S2   = S + 16 * (size_t)NN;
    float2*   UV   = (float2*)(S2 + 16 * (size_t)NN);
    float* out = (float*)d_out;

    k_hist <<<GPART, 256, 0, stream>>>(dst, HT);
    k_scanA<<<NBLK1, 256, 0, stream>>>(HT, PRE, BS, M);
    k_scanB<<<1, 512, 0, stream>>>(BS, NBLK1);
    k_scanC<<<(M + 255) / 256, 256, 0, stream>>>(PRE, BS, HT, M);
    k_part <<<GPART, 256, 0, stream>>>(src, dst, HT, EP);
    k_dinv <<<KB, 256, 0, stream>>>(HT, EP, dinv);
    k_xw1  <<<(NN + 255) / 256, 256, 0, stream>>>(x, W1, dinv, S);
    k_aggA <<<KB, 512, 0, stream>>>(HT, EP, S, dinv, b1, W2, S2);
    k_aggB <<<KB, 512, 0, stream>>>(HT, EP, S2, dinv, b2, Wfc, UV);
    k_pred <<<NE / 4 / 256, 256, 0, stream>>>(src, dst, UV, bfc, out);
}

// Round 15
// 314.314 us; speedup vs baseline: 2.7710x; 2.7566x over previous
//
#include <hip/hip_runtime.h>

// EdgeGCN v7: back to measured-fast CSR+gather (v3/v4), epilogues fused.
// Evidence: bucket-LDS-agg was 338-340us under two different atomic
// mechanisms (=> gather-MLP-bound, not atomic-bound); v4's per-node gather
// moved identical line traffic in 51us. v7 = that gather + in-register
// epilogue fusion (h1@W2 via width-16 shfl; uv via shfl_xor reduce),
// deleting k_h1s2, k_uv, and the AGG buffer.

constexpr int NN = 100000;
constexpr int NE = 3200000;
constexpr int FI = 128;
constexpr int HD = 16;
constexpr int SHIFT = 7;                    // 128 nodes per bucket
constexpr int KB = (NN + 127) >> 7;         // 782 buckets
constexpr int GPART = 256;                  // partition/hist blocks
constexpr int CH = NE / GPART;              // 12500 edges per block (exact)
constexpr int M = KB * GPART;               // 200192 histogram entries
constexpr int NBLK1 = M / 512;              // 391 scan blocks (exact)

// Per-block LDS histogram of buckets, transposed HT[k*G+b]. int4 x4 ILP.
__global__ __launch_bounds__(256) void k_hist(const int* __restrict__ dst,
                                              unsigned* __restrict__ HT) {
    __shared__ unsigned cnt[KB];
    for (int i = threadIdx.x; i < KB; i += 256) cnt[i] = 0;
    __syncthreads();
    const int4* dv = reinterpret_cast<const int4*>(dst) + blockIdx.x * (CH / 4);
    for (int v = threadIdx.x; v < CH / 4; v += 256) {
        int4 d4 = dv[v];
        atomicAdd(&cnt[d4.x >> SHIFT], 1u);
        atomicAdd(&cnt[d4.y >> SHIFT], 1u);
        atomicAdd(&cnt[d4.z >> SHIFT], 1u);
        atomicAdd(&cnt[d4.w >> SHIFT], 1u);
    }
    __syncthreads();
    for (int k = threadIdx.x; k < KB; k += 256)
        HT[(size_t)k * GPART + blockIdx.x] = cnt[k];
}

// Scan stage A: 512 elems/block -> pre, block totals -> bs.
__global__ __launch_bounds__(256) void k_scanA(const unsigned* __restrict__ in,
                                               unsigned* __restrict__ pre,
                                               unsigned* __restrict__ bs, int n) {
    __shared__ unsigned tsum[256];
    int t = threadIdx.x;
    int base = blockIdx.x * 512;
    int i0 = base + 2 * t, i1 = i0 + 1;
    unsigned a = (i0 < n) ? in[i0] : 0u;
    unsigned b = (i1 < n) ? in[i1] : 0u;
    tsum[t] = a + b;
    __syncthreads();
    #pragma unroll
    for (int off = 1; off < 256; off <<= 1) {
        unsigned v = (t >= off) ? tsum[t - off] : 0u;
        __syncthreads();
        tsum[t] += v;
        __syncthreads();
    }
    unsigned excl = tsum[t] - (a + b);
    if (t == 255) bs[blockIdx.x] = tsum[255];
    if (i0 < n) pre[i0] = excl;
    if (i1 < n) pre[i1] = excl + a;
}

// Stage B: exclusive scan of bs[nb] (nb <= 512) in place.
__global__ __launch_bounds__(512) void k_scanB(unsigned* __restrict__ bs, int nb) {
    __shared__ unsigned tsum[512];
    int t = threadIdx.x;
    unsigned v = (t < nb) ? bs[t] : 0u;
    tsum[t] = v;
    __syncthreads();
    #pragma unroll
    for (int off = 1; off < 512; off <<= 1) {
        unsigned w = (t >= off) ? tsum[t - off] : 0u;
        __syncthreads();
        tsum[t] += w;
        __syncthreads();
    }
    if (t < nb) bs[t] = tsum[t] - v;
}

// Stage C: out[i] = pre[i] + bs[i/512]  (out = HT in place: global run starts).
__global__ __launch_bounds__(256) void k_scanC(const unsigned* __restrict__ pre,
                                               const unsigned* __restrict__ bs,
                                               unsigned* __restrict__ out, int n) {
    int i = blockIdx.x * 256 + threadIdx.x;
    if (i < n) out[i] = pre[i] + bs[i >> 9];
}

// Partition: block b scatters its CH edges into bucket-grouped EP (LDS cursors).
// EP entry packs (d & 127) << 17 | s   (s < 2^17). int4 x4 ILP.
__global__ __launch_bounds__(256) void k_part(const int* __restrict__ src,
                                              const int* __restrict__ dst,
                                              const unsigned* __restrict__ HT,
                                              unsigned* __restrict__ EP) {
    __shared__ unsigned cur[KB];
    int b = blockIdx.x;
    for (int k = threadIdx.x; k < KB; k += 256)
        cur[k] = HT[(size_t)k * GPART + b];
    __syncthreads();
    const int4* dv = reinterpret_cast<const int4*>(dst) + b * (CH / 4);
    const int4* sv = reinterpret_cast<const int4*>(src) + b * (CH / 4);
    for (int v = threadIdx.x; v < CH / 4; v += 256) {
        int4 d4 = dv[v];
        int4 s4 = sv[v];
        unsigned p0 = atomicAdd(&cur[d4.x >> SHIFT], 1u);
        unsigned p1 = atomicAdd(&cur[d4.y >> SHIFT], 1u);
        unsigned p2 = atomicAdd(&cur[d4.z >> SHIFT], 1u);
        unsigned p3 = atomicAdd(&cur[d4.w >> SHIFT], 1u);
        EP[p0] = ((unsigned)(d4.x & 127) << 17) | (unsigned)s4.x;
        EP[p1] = ((unsigned)(d4.y & 127) << 17) | (unsigned)s4.y;
        EP[p2] = ((unsigned)(d4.z & 127) << 17) | (unsigned)s4.z;
        EP[p3] = ((unsigned)(d4.w & 127) << 17) | (unsigned)s4.w;
    }
}

// Fine sort: one block per bucket. Produces sidx (src grouped by dst),
// ptr (CSR offsets), dinv. All counting via LDS.
__global__ __launch_bounds__(256) void k_fine(const unsigned* __restrict__ HT,
                                              const unsigned* __restrict__ EP,
                                              int* __restrict__ sidx,
                                              int* __restrict__ ptr,
                                              float* __restrict__ dinv) {
    __shared__ unsigned cnt[128];
    __shared__ unsigned off[128];
    int k = blockIdx.x;
    int s0 = (int)HT[(size_t)k * GPART];
    int s1 = (k == KB - 1) ? NE : (int)HT[(size_t)(k + 1) * GPART];
    if (threadIdx.x < 128) cnt[threadIdx.x] = 0;
    __syncthreads();
    for (int j = s0 + (int)threadIdx.x; j < s1; j += 256)
        atomicAdd(&cnt[EP[j] >> 17], 1u);
    __syncthreads();
    if (threadIdx.x < 128) off[threadIdx.x] = cnt[threadIdx.x];
    __syncthreads();
    #pragma unroll
    for (int o = 1; o < 128; o <<= 1) {
        unsigned v = 0;
        if (threadIdx.x < 128 && threadIdx.x >= o) v = off[threadIdx.x - o];
        __syncthreads();
        if (threadIdx.x < 128) off[threadIdx.x] += v;  // inclusive scan
        __syncthreads();
    }
    int n0 = k << SHIFT;
    if (threadIdx.x < 128) {
        int n = n0 + (int)threadIdx.x;
        if (n < NN) {
            ptr[n] = s0 + (int)(off[threadIdx.x] - cnt[threadIdx.x]);
            dinv[n] = rsqrtf((float)cnt[threadIdx.x] + 1.0f);
        }
    }
    if (k == KB - 1 && threadIdx.x == 0) ptr[NN] = NE;
    __syncthreads();
    if (threadIdx.x < 128)
        cnt[threadIdx.x] = (unsigned)s0 + off[threadIdx.x] - cnt[threadIdx.x];  // cursors
    __syncthreads();
    for (int j = s0 + (int)threadIdx.x; j < s1; j += 256) {
        unsigned p = EP[j];
        unsigned pos = atomicAdd(&cnt[p >> 17], 1u);
        sidx[pos] = (int)(p & 0x1FFFFu);
    }
}

// S = (x @ W1) * dinv
__global__ __launch_bounds__(256) void k_xw1(const float* __restrict__ x,
                                             const float* __restrict__ W1,
                                             const float* __restrict__ dinv,
                                             float* __restrict__ S) {
    int i = blockIdx.x * 256 + threadIdx.x;
    if (i >= NN) return;
    const float4* xr = reinterpret_cast<const float4*>(x + (size_t)i * FI);
    float acc[HD];
    #pragma unroll
    for (int k = 0; k < HD; ++k) acc[k] = 0.f;
    #pragma unroll 8
    for (int jc = 0; jc < FI / 4; ++jc) {
        float4 xv = xr[jc];
        const float* w = W1 + jc * 4 * HD;
        #pragma unroll
        for (int k = 0; k < HD; ++k)
            acc[k] += xv.x * w[k] + xv.y * w[HD + k] + xv.z * w[2 * HD + k] + xv.w * w[3 * HD + k];
    }
    float dv = dinv[i];
    float4* out = reinterpret_cast<float4*>(S + (size_t)i * HD);
    #pragma unroll
    for (int q = 0; q < 4; ++q)
        out[q] = make_float4(acc[q * 4 + 0] * dv, acc[q * 4 + 1] * dv,
                             acc[q * 4 + 2] * dv, acc[q * 4 + 3] * dv);
}

// Layer-1 gather + fused epilogue. 16 lanes per node, x8 reg-prefetch.
// After the sum, lane k holds agg[k]; h1 = relu(dinv*(agg+S)+b1) lane-local;
// S2[k] = dinv * sum_j h1[j]*W2[j][k] via width-16 shfl broadcast.
__global__ __launch_bounds__(256) void k_gatherA(const int* __restrict__ ptr,
                                                 const int* __restrict__ sidx,
                                                 const float* __restrict__ S,
                                                 const float* __restrict__ dinv,
                                                 const float* __restrict__ b1,
                                                 const float* __restrict__ W2,
                                                 float* __restrict__ S2) {
    int t = blockIdx.x * 256 + threadIdx.x;       // NN*16 threads (6250 blocks)
    int i = t >> 4;
    int lane = t & 15;
    float w2c[16];                                 // W2 column 'lane' (L1-hot)
    #pragma unroll
    for (int j = 0; j < 16; ++j) w2c[j] = W2[j * HD + lane];
    int p0 = ptr[i], p1 = ptr[i + 1];
    float a0 = 0.f, a1 = 0.f, a2 = 0.f, a3 = 0.f;
    int j = p0;
    for (; j + 7 < p1; j += 8) {
        int v0 = sidx[j + 0], v1 = sidx[j + 1], v2 = sidx[j + 2], v3 = sidx[j + 3];
        int v4 = sidx[j + 4], v5 = sidx[j + 5], v6 = sidx[j + 6], v7 = sidx[j + 7];
        float s0 = S[(size_t)v0 * HD + lane];
        float s1 = S[(size_t)v1 * HD + lane];
        float s2 = S[(size_t)v2 * HD + lane];
        float s3 = S[(size_t)v3 * HD + lane];
        float s4 = S[(size_t)v4 * HD + lane];
        float s5 = S[(size_t)v5 * HD + lane];
        float s6 = S[(size_t)v6 * HD + lane];
        float s7 = S[(size_t)v7 * HD + lane];
        a0 += s0 + s4;
        a1 += s1 + s5;
        a2 += s2 + s6;
        a3 += s3 + s7;
    }
    for (; j < p1; ++j) a0 += S[(size_t)sidx[j] * HD + lane];
    float agg = (a0 + a1) + (a2 + a3);
    float dv = dinv[i];
    float self = S[(size_t)i * HD + lane];
    float h = fmaxf(dv * (agg + self) + b1[lane], 0.f);
    float s2acc = 0.f;
    #pragma unroll
    for (int jj = 0; jj < 16; ++jj) {
        float hj = __shfl(h, jj, 16);
        s2acc += hj * w2c[jj];
    }
    S2[(size_t)i * HD + lane] = s2acc * dv;
}

// Layer-2 gather + fused edge-scorer prep.
// h2 = dinv*(agg+S2)+b2 lane-local; (u,v) = (h2.Wfc[0:16], h2.Wfc[16:32])
// via width-16 shfl_xor reduction; lane 0 writes UV[i].
__global__ __launch_bounds__(256) void k_gatherB(const int* __restrict__ ptr,
                                                 const int* __restrict__ sidx,
                                                 const float* __restrict__ S2,
                                                 const float* __restrict__ dinv,
                                                 const float* __restrict__ b2,
                                                 const float* __restrict__ Wfc,
                                                 float2* __restrict__ UV) {
    int t = blockIdx.x * 256 + threadIdx.x;
    int i = t >> 4;
    int lane = t & 15;
    int p0 = ptr[i], p1 = ptr[i + 1];
    float a0 = 0.f, a1 = 0.f, a2 = 0.f, a3 = 0.f;
    int j = p0;
    for (; j + 7 < p1; j += 8) {
        int v0 = sidx[j + 0], v1 = sidx[j + 1], v2 = sidx[j + 2], v3 = sidx[j + 3];
        int v4 = sidx[j + 4], v5 = sidx[j + 5], v6 = sidx[j + 6], v7 = sidx[j + 7];
        float s0 = S2[(size_t)v0 * HD + lane];
        float s1 = S2[(size_t)v1 * HD + lane];
        float s2 = S2[(size_t)v2 * HD + lane];
        float s3 = S2[(size_t)v3 * HD + lane];
        float s4 = S2[(size_t)v4 * HD + lane];
        float s5 = S2[(size_t)v5 * HD + lane];
        float s6 = S2[(size_t)v6 * HD + lane];
        float s7 = S2[(size_t)v7 * HD + lane];
        a0 += s0 + s4;
        a1 += s1 + s5;
        a2 += s2 + s6;
        a3 += s3 + s7;
    }
    for (; j < p1; ++j) a0 += S2[(size_t)sidx[j] * HD + lane];
    float agg = (a0 + a1) + (a2 + a3);
    float dv = dinv[i];
    float self = S2[(size_t)i * HD + lane];
    float h = dv * (agg + self) + b2[lane];
    float u = h * Wfc[lane];
    float v = h * Wfc[HD + lane];
    #pragma unroll
    for (int o = 8; o; o >>= 1) {
        u += __shfl_xor(u, o, 16);
        v += __shfl_xor(v, o, 16);
    }
    if (lane == 0) UV[i] = make_float2(u, v);
}

__global__ __launch_bounds__(256) void k_pred(const int* __restrict__ src,
                                              const int* __restrict__ dst,
                                              const float2* __restrict__ UV,
                                              const float* __restrict__ bfc,
                                              float* __restrict__ out) {
    int t = blockIdx.x * 256 + threadIdx.x;       // NE/4 threads
    int4 s4 = reinterpret_cast<const int4*>(src)[t];
    int4 d4 = reinterpret_cast<const int4*>(dst)[t];
    float bb = bfc[0];
    float4 o;
    o.x = UV[s4.x].x + UV[d4.x].y + bb;
    o.y = UV[s4.y].x + UV[d4.y].y + bb;
    o.z = UV[s4.z].x + UV[d4.z].y + bb;
    o.w = UV[s4.w].x + UV[d4.w].y + bb;
    reinterpret_cast<float4*>(out)[t] = o;
}

extern "C" void kernel_launch(void* const* d_in, const int* in_sizes, int n_in,
                              void* d_out, int out_size, void* d_ws, size_t ws_size,
                              hipStream_t stream) {
    const float* x   = (const float*)d_in[0];
    const int*   ei  = (const int*)d_in[1];
    const float* W1  = (const float*)d_in[2];
    const float* b1  = (const float*)d_in[3];
    const float* W2  = (const float*)d_in[4];
    const float* b2  = (const float*)d_in[5];
    const float* Wfc = (const float*)d_in[6];
    const float* bfc = (const float*)d_in[7];
    const int* src = ei;            // edge_index[0]
    const int* dst = ei + NE;       // edge_index[1]

    // ws layout (4B units):
    //   HT[M] | BS[512] | PRE[M] | EP[E] | sidx[E] | ptr[N+2] | dinv[N] | S[16N] | S2[16N] | UV[2N]
    unsigned* ws32 = (unsigned*)d_ws;
    unsigned* HT   = ws32;
    unsigned* BS   = HT + M;
    unsigned* PRE  = BS + 512;
    unsigned* EP   = PRE + M;
    int*      sidx = (int*)(EP + NE);
    int*      ptr  = sidx + NE;
    float*    dinv = (float*)(ptr + NN + 2);
    float*    S    = dinv + NN;
    float*    S2   = S + 16 * (size_t)NN;
    float2*   UV   = (float2*)(S2 + 16 * (size_t)NN);
    float* out = (float*)d_out;

    k_hist   <<<GPART, 256, 0, stream>>>(dst, HT);
    k_scanA  <<<NBLK1, 256, 0, stream>>>(HT, PRE, BS, M);
    k_scanB  <<<1, 512, 0, stream>>>(BS, NBLK1);
    k_scanC  <<<(M + 255) / 256, 256, 0, stream>>>(PRE, BS, HT, M);
    k_part   <<<GPART, 256, 0, stream>>>(src, dst, HT, EP);
    k_fine   <<<KB, 256, 0, stream>>>(HT, EP, sidx, ptr, dinv);
    k_xw1    <<<(NN + 255) / 256, 256, 0, stream>>>(x, W1, dinv, S);
    k_gatherA<<<NN * HD / 256, 256, 0, stream>>>(ptr, sidx, S, dinv, b1, W2, S2);
    k_gatherB<<<NN * HD / 256, 256, 0, stream>>>(ptr, sidx, S2, dinv, b2, Wfc, UV);
    k_pred   <<<NE / 4 / 256, 256, 0, stream>>>(src, dst, UV, bfc, out);
}

// Round 18
// 290.139 us; speedup vs baseline: 3.0019x; 1.0833x over previous
//
#include <hip/hip_runtime.h>
#include <hip/hip_fp16.h>

// EdgeGCN v8: v7 + fp16 storage for S/S2 feature tables.
// Gathers fetched 143MB each (one 64B line per edge: the fp32 row IS the
// line). fp16 rows are 32B -> 2 rows/line, halving line traffic; accum
// stays fp32. Everything else identical to v7 (314us).

constexpr int NN = 100000;
constexpr int NE = 3200000;
constexpr int FI = 128;
constexpr int HD = 16;
constexpr int SHIFT = 7;                    // 128 nodes per bucket
constexpr int KB = (NN + 127) >> 7;         // 782 buckets
constexpr int GPART = 256;                  // partition/hist blocks
constexpr int CH = NE / GPART;              // 12500 edges per block (exact)
constexpr int M = KB * GPART;               // 200192 histogram entries
constexpr int NBLK1 = M / 512;              // 391 scan blocks (exact)

// Per-block LDS histogram of buckets, transposed HT[k*G+b]. int4 x4 ILP.
__global__ __launch_bounds__(256) void k_hist(const int* __restrict__ dst,
                                              unsigned* __restrict__ HT) {
    __shared__ unsigned cnt[KB];
    for (int i = threadIdx.x; i < KB; i += 256) cnt[i] = 0;
    __syncthreads();
    const int4* dv = reinterpret_cast<const int4*>(dst) + blockIdx.x * (CH / 4);
    for (int v = threadIdx.x; v < CH / 4; v += 256) {
        int4 d4 = dv[v];
        atomicAdd(&cnt[d4.x >> SHIFT], 1u);
        atomicAdd(&cnt[d4.y >> SHIFT], 1u);
        atomicAdd(&cnt[d4.z >> SHIFT], 1u);
        atomicAdd(&cnt[d4.w >> SHIFT], 1u);
    }
    __syncthreads();
    for (int k = threadIdx.x; k < KB; k += 256)
        HT[(size_t)k * GPART + blockIdx.x] = cnt[k];
}

// Scan stage A: 512 elems/block -> pre, block totals -> bs.
__global__ __launch_bounds__(256) void k_scanA(const unsigned* __restrict__ in,
                                               unsigned* __restrict__ pre,
                                               unsigned* __restrict__ bs, int n) {
    __shared__ unsigned tsum[256];
    int t = threadIdx.x;
    int base = blockIdx.x * 512;
    int i0 = base + 2 * t, i1 = i0 + 1;
    unsigned a = (i0 < n) ? in[i0] : 0u;
    unsigned b = (i1 < n) ? in[i1] : 0u;
    tsum[t] = a + b;
    __syncthreads();
    #pragma unroll
    for (int off = 1; off < 256; off <<= 1) {
        unsigned v = (t >= off) ? tsum[t - off] : 0u;
        __syncthreads();
        tsum[t] += v;
        __syncthreads();
    }
    unsigned excl = tsum[t] - (a + b);
    if (t == 255) bs[blockIdx.x] = tsum[255];
    if (i0 < n) pre[i0] = excl;
    if (i1 < n) pre[i1] = excl + a;
}

// Stage B: exclusive scan of bs[nb] (nb <= 512) in place.
__global__ __launch_bounds__(512) void k_scanB(unsigned* __restrict__ bs, int nb) {
    __shared__ unsigned tsum[512];
    int t = threadIdx.x;
    unsigned v = (t < nb) ? bs[t] : 0u;
    tsum[t] = v;
    __syncthreads();
    #pragma unroll
    for (int off = 1; off < 512; off <<= 1) {
        unsigned w = (t >= off) ? tsum[t - off] : 0u;
        __syncthreads();
        tsum[t] += w;
        __syncthreads();
    }
    if (t < nb) bs[t] = tsum[t] - v;
}

// Stage C: out[i] = pre[i] + bs[i/512]  (out = HT in place: global run starts).
__global__ __launch_bounds__(256) void k_scanC(const unsigned* __restrict__ pre,
                                               const unsigned* __restrict__ bs,
                                               unsigned* __restrict__ out, int n) {
    int i = blockIdx.x * 256 + threadIdx.x;
    if (i < n) out[i] = pre[i] + bs[i >> 9];
}

// Partition: block b scatters its CH edges into bucket-grouped EP (LDS cursors).
// EP entry packs (d & 127) << 17 | s   (s < 2^17). int4 x4 ILP.
__global__ __launch_bounds__(256) void k_part(const int* __restrict__ src,
                                              const int* __restrict__ dst,
                                              const unsigned* __restrict__ HT,
                                              unsigned* __restrict__ EP) {
    __shared__ unsigned cur[KB];
    int b = blockIdx.x;
    for (int k = threadIdx.x; k < KB; k += 256)
        cur[k] = HT[(size_t)k * GPART + b];
    __syncthreads();
    const int4* dv = reinterpret_cast<const int4*>(dst) + b * (CH / 4);
    const int4* sv = reinterpret_cast<const int4*>(src) + b * (CH / 4);
    for (int v = threadIdx.x; v < CH / 4; v += 256) {
        int4 d4 = dv[v];
        int4 s4 = sv[v];
        unsigned p0 = atomicAdd(&cur[d4.x >> SHIFT], 1u);
        unsigned p1 = atomicAdd(&cur[d4.y >> SHIFT], 1u);
        unsigned p2 = atomicAdd(&cur[d4.z >> SHIFT], 1u);
        unsigned p3 = atomicAdd(&cur[d4.w >> SHIFT], 1u);
        EP[p0] = ((unsigned)(d4.x & 127) << 17) | (unsigned)s4.x;
        EP[p1] = ((unsigned)(d4.y & 127) << 17) | (unsigned)s4.y;
        EP[p2] = ((unsigned)(d4.z & 127) << 17) | (unsigned)s4.z;
        EP[p3] = ((unsigned)(d4.w & 127) << 17) | (unsigned)s4.w;
    }
}

// Fine sort: one block per bucket. Produces sidx (src grouped by dst),
// ptr (CSR offsets), dinv. All counting via LDS.
__global__ __launch_bounds__(256) void k_fine(const unsigned* __restrict__ HT,
                                              const unsigned* __restrict__ EP,
                                              int* __restrict__ sidx,
                                              int* __restrict__ ptr,
                                              float* __restrict__ dinv) {
    __shared__ unsigned cnt[128];
    __shared__ unsigned off[128];
    int k = blockIdx.x;
    int s0 = (int)HT[(size_t)k * GPART];
    int s1 = (k == KB - 1) ? NE : (int)HT[(size_t)(k + 1) * GPART];
    if (threadIdx.x < 128) cnt[threadIdx.x] = 0;
    __syncthreads();
    for (int j = s0 + (int)threadIdx.x; j < s1; j += 256)
        atomicAdd(&cnt[EP[j] >> 17], 1u);
    __syncthreads();
    if (threadIdx.x < 128) off[threadIdx.x] = cnt[threadIdx.x];
    __syncthreads();
    #pragma unroll
    for (int o = 1; o < 128; o <<= 1) {
        unsigned v = 0;
        if (threadIdx.x < 128 && threadIdx.x >= o) v = off[threadIdx.x - o];
        __syncthreads();
        if (threadIdx.x < 128) off[threadIdx.x] += v;  // inclusive scan
        __syncthreads();
    }
    int n0 = k << SHIFT;
    if (threadIdx.x < 128) {
        int n = n0 + (int)threadIdx.x;
        if (n < NN) {
            ptr[n] = s0 + (int)(off[threadIdx.x] - cnt[threadIdx.x]);
            dinv[n] = rsqrtf((float)cnt[threadIdx.x] + 1.0f);
        }
    }
    if (k == KB - 1 && threadIdx.x == 0) ptr[NN] = NE;
    __syncthreads();
    if (threadIdx.x < 128)
        cnt[threadIdx.x] = (unsigned)s0 + off[threadIdx.x] - cnt[threadIdx.x];  // cursors
    __syncthreads();
    for (int j = s0 + (int)threadIdx.x; j < s1; j += 256) {
        unsigned p = EP[j];
        unsigned pos = atomicAdd(&cnt[p >> 17], 1u);
        sidx[pos] = (int)(p & 0x1FFFFu);
    }
}

// S = (x @ W1) * dinv, stored fp16 (row = 32B).
__global__ __launch_bounds__(256) void k_xw1(const float* __restrict__ x,
                                             const float* __restrict__ W1,
                                             const float* __restrict__ dinv,
                                             __half* __restrict__ S) {
    int i = blockIdx.x * 256 + threadIdx.x;
    if (i >= NN) return;
    const float4* xr = reinterpret_cast<const float4*>(x + (size_t)i * FI);
    float acc[HD];
    #pragma unroll
    for (int k = 0; k < HD; ++k) acc[k] = 0.f;
    #pragma unroll 8
    for (int jc = 0; jc < FI / 4; ++jc) {
        float4 xv = xr[jc];
        const float* w = W1 + jc * 4 * HD;
        #pragma unroll
        for (int k = 0; k < HD; ++k)
            acc[k] += xv.x * w[k] + xv.y * w[HD + k] + xv.z * w[2 * HD + k] + xv.w * w[3 * HD + k];
    }
    float dv = dinv[i];
    __half hrow[HD];
    #pragma unroll
    for (int k = 0; k < HD; ++k) hrow[k] = __float2half(acc[k] * dv);
    uint4* o = reinterpret_cast<uint4*>(S + (size_t)i * HD);
    const uint4* hr = reinterpret_cast<const uint4*>(hrow);
    o[0] = hr[0];
    o[1] = hr[1];
}

// Layer-1 gather + fused epilogue (fp16 S in, fp16 S2 out, fp32 accum).
__global__ __launch_bounds__(256) void k_gatherA(const int* __restrict__ ptr,
                                                 const int* __restrict__ sidx,
                                                 const __half* __restrict__ S,
                                                 const float* __restrict__ dinv,
                                                 const float* __restrict__ b1,
                                                 const float* __restrict__ W2,
                                                 __half* __restrict__ S2) {
    int t = blockIdx.x * 256 + threadIdx.x;       // NN*16 threads (6250 blocks)
    int i = t >> 4;
    int lane = t & 15;
    float w2c[16];                                 // W2 column 'lane' (L1-hot)
    #pragma unroll
    for (int j = 0; j < 16; ++j) w2c[j] = W2[j * HD + lane];
    int p0 = ptr[i], p1 = ptr[i + 1];
    float a0 = 0.f, a1 = 0.f, a2 = 0.f, a3 = 0.f;
    int j = p0;
    for (; j + 7 < p1; j += 8) {
        int v0 = sidx[j + 0], v1 = sidx[j + 1], v2 = sidx[j + 2], v3 = sidx[j + 3];
        int v4 = sidx[j + 4], v5 = sidx[j + 5], v6 = sidx[j + 6], v7 = sidx[j + 7];
        float s0 = __half2float(S[(size_t)v0 * HD + lane]);
        float s1 = __half2float(S[(size_t)v1 * HD + lane]);
        float s2 = __half2float(S[(size_t)v2 * HD + lane]);
        float s3 = __half2float(S[(size_t)v3 * HD + lane]);
        float s4 = __half2float(S[(size_t)v4 * HD + lane]);
        float s5 = __half2float(S[(size_t)v5 * HD + lane]);
        float s6 = __half2float(S[(size_t)v6 * HD + lane]);
        float s7 = __half2float(S[(size_t)v7 * HD + lane]);
        a0 += s0 + s4;
        a1 += s1 + s5;
        a2 += s2 + s6;
        a3 += s3 + s7;
    }
    for (; j < p1; ++j) a0 += __half2float(S[(size_t)sidx[j] * HD + lane]);
    float agg = (a0 + a1) + (a2 + a3);
    float dv = dinv[i];
    float self = __half2float(S[(size_t)i * HD + lane]);
    float h = fmaxf(dv * (agg + self) + b1[lane], 0.f);
    float s2acc = 0.f;
    #pragma unroll
    for (int jj = 0; jj < 16; ++jj) {
        float hj = __shfl(h, jj, 16);
        s2acc += hj * w2c[jj];
    }
    S2[(size_t)i * HD + lane] = __float2half(s2acc * dv);
}

// Layer-2 gather + fused edge-scorer prep (fp16 S2 in).
__global__ __launch_bounds__(256) void k_gatherB(const int* __restrict__ ptr,
                                                 const int* __restrict__ sidx,
                                                 const __half* __restrict__ S2,
                                                 const float* __restrict__ dinv,
                                                 const float* __restrict__ b2,
                                                 const float* __restrict__ Wfc,
                                                 float2* __restrict__ UV) {
    int t = blockIdx.x * 256 + threadIdx.x;
    int i = t >> 4;
    int lane = t & 15;
    int p0 = ptr[i], p1 = ptr[i + 1];
    float a0 = 0.f, a1 = 0.f, a2 = 0.f, a3 = 0.f;
    int j = p0;
    for (; j + 7 < p1; j += 8) {
        int v0 = sidx[j + 0], v1 = sidx[j + 1], v2 = sidx[j + 2], v3 = sidx[j + 3];
        int v4 = sidx[j + 4], v5 = sidx[j + 5], v6 = sidx[j + 6], v7 = sidx[j + 7];
        float s0 = __half2float(S2[(size_t)v0 * HD + lane]);
        float s1 = __half2float(S2[(size_t)v1 * HD + lane]);
        float s2 = __half2float(S2[(size_t)v2 * HD + lane]);
        float s3 = __half2float(S2[(size_t)v3 * HD + lane]);
        float s4 = __half2float(S2[(size_t)v4 * HD + lane]);
        float s5 = __half2float(S2[(size_t)v5 * HD + lane]);
        float s6 = __half2float(S2[(size_t)v6 * HD + lane]);
        float s7 = __half2float(S2[(size_t)v7 * HD + lane]);
        a0 += s0 + s4;
        a1 += s1 + s5;
        a2 += s2 + s6;
        a3 += s3 + s7;
    }
    for (; j < p1; ++j) a0 += __half2float(S2[(size_t)sidx[j] * HD + lane]);
    float agg = (a0 + a1) + (a2 + a3);
    float dv = dinv[i];
    float self = __half2float(S2[(size_t)i * HD + lane]);
    float h = dv * (agg + self) + b2[lane];
    float u = h * Wfc[lane];
    float v = h * Wfc[HD + lane];
    #pragma unroll
    for (int o = 8; o; o >>= 1) {
        u += __shfl_xor(u, o, 16);
        v += __shfl_xor(v, o, 16);
    }
    if (lane == 0) UV[i] = make_float2(u, v);
}

__global__ __launch_bounds__(256) void k_pred(const int* __restrict__ src,
                                              const int* __restrict__ dst,
                                              const float2* __restrict__ UV,
                                              const float* __restrict__ bfc,
                                              float* __restrict__ out) {
    int t = blockIdx.x * 256 + threadIdx.x;       // NE/4 threads
    int4 s4 = reinterpret_cast<const int4*>(src)[t];
    int4 d4 = reinterpret_cast<const int4*>(dst)[t];
    float bb = bfc[0];
    float4 o;
    o.x = UV[s4.x].x + UV[d4.x].y + bb;
    o.y = UV[s4.y].x + UV[d4.y].y + bb;
    o.z = UV[s4.z].x + UV[d4.z].y + bb;
    o.w = UV[s4.w].x + UV[d4.w].y + bb;
    reinterpret_cast<float4*>(out)[t] = o;
}

extern "C" void kernel_launch(void* const* d_in, const int* in_sizes, int n_in,
                              void* d_out, int out_size, void* d_ws, size_t ws_size,
                              hipStream_t stream) {
    const float* x   = (const float*)d_in[0];
    const int*   ei  = (const int*)d_in[1];
    const float* W1  = (const float*)d_in[2];
    const float* b1  = (const float*)d_in[3];
    const float* W2  = (const float*)d_in[4];
    const float* b2  = (const float*)d_in[5];
    const float* Wfc = (const float*)d_in[6];
    const float* bfc = (const float*)d_in[7];
    const int* src = ei;            // edge_index[0]
    const int* dst = ei + NE;       // edge_index[1]

    // ws layout (4B units; S/S2 are fp16 but given 16N 4B slots each - slack ok):
    //   HT[M] | BS[512] | PRE[M] | EP[E] | sidx[E] | ptr[N+2] | dinv[N] | S | S2 | UV
    unsigned* ws32 = (unsigned*)d_ws;
    unsigned* HT   = ws32;
    unsigned* BS   = HT + M;
    unsigned* PRE  = BS + 512;
    unsigned* EP   = PRE + M;
    int*      sidx = (int*)(EP + NE);
    int*      ptr  = sidx + NE;
    float*    dinv = (float*)(ptr + NN + 2);
    __half*   S    = (__half*)(dinv + NN);                    // 16N halves (8N floats)
    __half*   S2   = (__half*)(dinv + NN + 8 * (size_t)NN);   // 16N halves
    float2*   UV   = (float2*)(dinv + NN + 16 * (size_t)NN);  // 2N floats
    float* out = (float*)d_out;

    k_hist   <<<GPART, 256, 0, stream>>>(dst, HT);
    k_scanA  <<<NBLK1, 256, 0, stream>>>(HT, PRE, BS, M);
    k_scanB  <<<1, 512, 0, stream>>>(BS, NBLK1);
    k_scanC  <<<(M + 255) / 256, 256, 0, stream>>>(PRE, BS, HT, M);
    k_part   <<<GPART, 256, 0, stream>>>(src, dst, HT, EP);
    k_fine   <<<KB, 256, 0, stream>>>(HT, EP, sidx, ptr, dinv);
    k_xw1    <<<(NN + 255) / 256, 256, 0, stream>>>(x, W1, dinv, S);
    k_gatherA<<<NN * HD / 256, 256, 0, stream>>>(ptr, sidx, S, dinv, b1, W2, S2);
    k_gatherB<<<NN * HD / 256, 256, 0, stream>>>(ptr, sidx, S2, dinv, b2, Wfc, UV);
    k_pred   <<<NE / 4 / 256, 256, 0, stream>>>(src, dst, UV, bfc, out);
}